// Round 1
// baseline (729.675 us; speedup 1.0000x reference)
//
#include <hip/hip_runtime.h>

// SparseGraphConv: y = W @ concat([x, A1x, A1^2 x, A2 x, A2^2 x]) + b
// B=16, C=64, N=2048, T=12, C_OUT=64.
//
// Strategy:
//   1. cvt_a:   A1,A2 f32 -> bf16 rows of Astack[8192,2048] (+ transposed copies for A^2 GEMM)
//   2. gemm(z=2): A1^2 = A1 @ A1 (via A1^T as BT), A2^2 likewise -> remaining Astack rows
//   3. pack_x:  x[b,c,n,t] f32 -> XtT[(b*12+t)*64+c][n] bf16   (B-operand, k-contiguous rows)
//   4. gemm:    Y[8192, 12288] = Astack @ XtT^T   (the 4 node-mixings, one GEMM, 412 GFLOP)
//   5. conv:    per node n: y[b,o,n,t] = bias[o] + sum_k W_k @ h_k  (MFMA, h_k from x / Y)

typedef __attribute__((ext_vector_type(8))) __bf16 bf16x8;
typedef __attribute__((ext_vector_type(4))) float f32x4;
typedef __attribute__((ext_vector_type(8))) unsigned short u16x8;
typedef unsigned short u16;
typedef unsigned int u32;

__device__ __forceinline__ u16 f2bf(float f) {
    u32 u = __float_as_uint(f);
    u32 r = u + 0x7FFFu + ((u >> 16) & 1u);   // round-to-nearest-even
    return (u16)(r >> 16);
}

__device__ __forceinline__ void gload16(const void* g, void* l) {
    // async global->LDS, 16B per lane; LDS dest = wave-uniform base + lane*16
    __builtin_amdgcn_global_load_lds((const __attribute__((address_space(1))) void*)g,
                                     (__attribute__((address_space(3))) void*)l, 16, 0, 0);
}

// ---------------------------------------------------------------------------
// W f32 [64,320] -> Wbf bf16 [5][64][64]:  Wbf[(k*64+o)*64+c] = W[o*320 + k*64 + c]
__global__ __launch_bounds__(256)
void cvt_w_kernel(const float* __restrict__ W, u16* __restrict__ wbf) {
    int i = blockIdx.x * 256 + threadIdx.x;
    if (i < 5 * 64 * 64) {
        int c = i & 63;
        int o = (i >> 6) & 63;
        int k = i >> 12;
        wbf[i] = f2bf(W[o * 320 + k * 64 + c]);
    }
}

// ---------------------------------------------------------------------------
// A1,A2 f32 [2048,2048] -> bf16 direct (Astack rows 0..2047 / 4096..6143) + transposed
__global__ __launch_bounds__(256)
void cvt_a_kernel(const float* __restrict__ A1, const float* __restrict__ A2,
                  u16* __restrict__ astack, u16* __restrict__ a1t, u16* __restrict__ a2t) {
    __shared__ float lt[64][65];
    int bid = blockIdx.x;
    int mat = bid >> 10;              // 1024 64x64 tiles per matrix
    int ti = bid & 1023;
    int tr = (ti >> 5) << 6;
    int tc = (ti & 31) << 6;
    const float* src = mat ? A2 : A1;
    u16* dstA = astack + (size_t)(mat ? 4096 : 0) * 2048;
    u16* dstT = mat ? a2t : a1t;
    int tid = threadIdx.x;
    int rr = tid >> 4;                // 0..15
    int cc = (tid & 15) << 2;         // 0..60
#pragma unroll
    for (int p = 0; p < 4; ++p) {
        int row = p * 16 + rr;
        float4 v = *(const float4*)&src[(size_t)(tr + row) * 2048 + tc + cc];
        ushort4 o;
        o.x = f2bf(v.x); o.y = f2bf(v.y); o.z = f2bf(v.z); o.w = f2bf(v.w);
        *(ushort4*)&dstA[(size_t)(tr + row) * 2048 + tc + cc] = o;
        lt[row][cc + 0] = v.x; lt[row][cc + 1] = v.y;
        lt[row][cc + 2] = v.z; lt[row][cc + 3] = v.w;
    }
    __syncthreads();
#pragma unroll
    for (int p = 0; p < 4; ++p) {
        int row = p * 16 + rr;        // row of the transposed tile = original col
        ushort4 o;
        o.x = f2bf(lt[cc + 0][row]); o.y = f2bf(lt[cc + 1][row]);
        o.z = f2bf(lt[cc + 2][row]); o.w = f2bf(lt[cc + 3][row]);
        *(ushort4*)&dstT[(size_t)(tc + row) * 2048 + tr + cc] = o;
    }
}

// ---------------------------------------------------------------------------
// x[b,c,n,t] f32 -> XtT[(bl*12+t)*64+c][n] bf16 (chunk-local over bl in [0,Gb))
__global__ __launch_bounds__(256)
void pack_x_kernel(const float* __restrict__ x, u16* __restrict__ XtT, int b0, int Gb) {
    int tid = blockIdx.x * 256 + threadIdx.x;   // Gb*64*2048 threads exactly
    int n = tid & 2047;
    int bc = tid >> 11;
    int c = bc & 63;
    int bl = bc >> 6;
    const float* src = x + ((size_t)((b0 + bl) * 64 + c) * 2048 + n) * 12;
    float4 v0 = *(const float4*)(src + 0);
    float4 v1 = *(const float4*)(src + 4);
    float4 v2 = *(const float4*)(src + 8);
    float vv[12];
    *(float4*)&vv[0] = v0; *(float4*)&vv[4] = v1; *(float4*)&vv[8] = v2;
    u16* dst = XtT + (size_t)(bl * 12 * 64 + c) * 2048 + n;
#pragma unroll
    for (int t = 0; t < 12; ++t)
        dst[(size_t)t * 64 * 2048] = f2bf(vv[t]);   // wave-contiguous over n
}

// ---------------------------------------------------------------------------
// C[M,N] = A[M,K] @ BT[N,K]^T, all bf16 row-major, f32 accum, bf16 out.
// 128x128 tile, BK=64, 4 waves, global_load_lds(16B), XOR bank-swizzle, XCD swizzle.
// gridDim.z selects pointer set (z=0: set0, z=1: set1) so two GEMMs share one launch.
__global__ __launch_bounds__(256, 2)
void gemm_bt_kernel(const u16* __restrict__ A0, const u16* __restrict__ B0, u16* __restrict__ C0,
                    const u16* __restrict__ A1p, const u16* __restrict__ B1p, u16* __restrict__ C1p,
                    int K, int lda, int ldb, int ldc) {
    const u16* A  = blockIdx.z ? A1p : A0;
    const u16* BT = blockIdx.z ? B1p : B0;
    u16* C        = blockIdx.z ? C1p : C0;

    __shared__ u16 lA[128 * 64];
    __shared__ u16 lB[128 * 64];

    // bijective XCD swizzle (nwg % 8 == 0 for all our launches)
    int gx = gridDim.x;
    int nwg = gx * gridDim.y;
    int orig = blockIdx.y * gx + blockIdx.x;
    int swz = (orig & 7) * (nwg >> 3) + (orig >> 3);
    int by = swz / gx, bx = swz - by * gx;

    const int m0 = by * 128, n0 = bx * 128;
    const int tid = threadIdx.x;
    const int w = tid >> 6, l = tid & 63;
    const int wr = w >> 1, wc = w & 1;

    f32x4 acc[4][4] = {};

    // staging: segment s covers LDS rows [8s, 8s+8); lane l -> row 8s+(l>>3),
    // physical col-group l&7, which must hold logical col-group (l&7)^(row&7)
    const int srow = l >> 3;
    const int scol = ((l & 7) ^ srow) * 8;

    for (int kt = 0; kt < K; kt += 64) {
#pragma unroll
        for (int r = 0; r < 4; ++r) {
            int s = w * 4 + r;
            int row = s * 8 + srow;
            gload16(A + (size_t)(m0 + row) * lda + kt + scol, &lA[s * 512]);
        }
#pragma unroll
        for (int r = 0; r < 4; ++r) {
            int s = w * 4 + r;
            int row = s * 8 + srow;
            gload16(BT + (size_t)(n0 + row) * ldb + kt + scol, &lB[s * 512]);
        }
        __syncthreads();   // compiler emits s_waitcnt vmcnt(0) before s_barrier
#pragma unroll
        for (int kk = 0; kk < 2; ++kk) {
            bf16x8 af[4], bfr[4];
            const int cg = ((kk * 4 + (l >> 4)) ^ (l & 7)) * 8;  // swizzled read col
#pragma unroll
            for (int i = 0; i < 4; ++i)
                af[i] = *(const bf16x8*)&lA[(wr * 64 + i * 16 + (l & 15)) * 64 + cg];
#pragma unroll
            for (int j = 0; j < 4; ++j)
                bfr[j] = *(const bf16x8*)&lB[(wc * 64 + j * 16 + (l & 15)) * 64 + cg];
#pragma unroll
            for (int i = 0; i < 4; ++i)
#pragma unroll
                for (int j = 0; j < 4; ++j)
                    acc[i][j] = __builtin_amdgcn_mfma_f32_16x16x32_bf16(af[i], bfr[j], acc[i][j], 0, 0, 0);
        }
        __syncthreads();
    }

    // C/D layout: col = lane&15, row = (lane>>4)*4 + reg  [m89-verified]
    const int lr = (l >> 4) * 4, lc = l & 15;
#pragma unroll
    for (int i = 0; i < 4; ++i) {
        int row = m0 + wr * 64 + i * 16 + lr;
#pragma unroll
        for (int j = 0; j < 4; ++j) {
            int col = n0 + wc * 64 + j * 16 + lc;
            u16* p = C + (size_t)row * ldc + col;
#pragma unroll
            for (int q = 0; q < 4; ++q)
                p[(size_t)q * ldc] = f2bf(acc[i][j][q]);
        }
    }
}

// ---------------------------------------------------------------------------
// Final 1x1 conv: per block, nPerBlk nodes x Gb batches (192 output cols).
// y[b,o,n,t] = bias[o] + sum_{k=0..4} sum_c Wk[o,c] * h_k[c, (b,t)]
//   h_0 from x (f32->bf16), h_{1..4} from Y rows (k-1)*2048+n (contiguous bf16).
__global__ __launch_bounds__(256, 2)
void conv_kernel(const float* __restrict__ x, const u16* __restrict__ Y,
                 const u16* __restrict__ Wbf, const float* __restrict__ bias,
                 float* __restrict__ yout, int b0, int Gb, int nPerBlk, int ldy) {
    __shared__ u16 lh[192 * 72];   // [j'=(nl,bl,t)][c], padded 64->72 (bank spread)
    const int colsPerN = Gb * 12;
    const int n0 = blockIdx.x * nPerBlk;
    const int tid = threadIdx.x;
    const int w = tid >> 6, l = tid & 63;
    f32x4 acc[4][3] = {};

    for (int k = 0; k < 5; ++k) {
        __syncthreads();   // protect lh from previous iteration's readers
        if (k == 0) {
            const int tot = nPerBlk * Gb * 64;   // = 1024
            for (int it = tid; it < tot; it += 256) {
                int c = it & 63;
                int bn = it >> 6;
                int bl = bn % Gb;
                int nl = bn / Gb;
                const float* src = x + ((size_t)((b0 + bl) * 64 + c) * 2048 + (n0 + nl)) * 12;
                float4 v0 = *(const float4*)(src + 0);
                float4 v1 = *(const float4*)(src + 4);
                float4 v2 = *(const float4*)(src + 8);
                float vv[12];
                *(float4*)&vv[0] = v0; *(float4*)&vv[4] = v1; *(float4*)&vv[8] = v2;
                u16* d = &lh[(nl * colsPerN + bl * 12) * 72 + c];
#pragma unroll
                for (int t = 0; t < 12; ++t) d[t * 72] = f2bf(vv[t]);
            }
        } else {
            for (int it = tid; it < 1536; it += 256) {   // 192*64/8 u16x8 chunks
                int e8 = it << 3;
                int c = e8 & 63;
                int jj = e8 >> 6;
                int nl = jj / colsPerN;
                int rem = jj - nl * colsPerN;
                const u16* src = Y + (size_t)((k - 1) * 2048 + n0 + nl) * ldy + rem * 64 + c;
                *(u16x8*)&lh[jj * 72 + c] = *(const u16x8*)src;
            }
        }
        __syncthreads();
#pragma unroll
        for (int kk = 0; kk < 2; ++kk) {
            bf16x8 wf[4], hf[3];
#pragma unroll
            for (int i = 0; i < 4; ++i)
                wf[i] = *(const bf16x8*)&Wbf[(size_t)(k * 64 + i * 16 + (l & 15)) * 64 + kk * 32 + (l >> 4) * 8];
#pragma unroll
            for (int j = 0; j < 3; ++j)
                hf[j] = *(const bf16x8*)&lh[(w * 48 + j * 16 + (l & 15)) * 72 + kk * 32 + (l >> 4) * 8];
#pragma unroll
            for (int i = 0; i < 4; ++i)
#pragma unroll
                for (int j = 0; j < 3; ++j)
                    acc[i][j] = __builtin_amdgcn_mfma_f32_16x16x32_bf16(wf[i], hf[j], acc[i][j], 0, 0, 0);
        }
    }

    const int lr = (l >> 4) * 4, lc = l & 15;
#pragma unroll
    for (int j = 0; j < 3; ++j) {
        int jj = w * 48 + j * 16 + lc;
        int nl = jj / colsPerN;
        int rem = jj - nl * colsPerN;
        int bl = rem / 12;
        int t = rem - bl * 12;
#pragma unroll
        for (int i = 0; i < 4; ++i) {
#pragma unroll
            for (int q = 0; q < 4; ++q) {
                int o = i * 16 + lr + q;
                yout[((size_t)((b0 + bl) * 64 + o) * 2048 + (n0 + nl)) * 12 + t] = acc[i][j][q] + bias[o];
            }
        }
    }
}

// ---------------------------------------------------------------------------
extern "C" void kernel_launch(void* const* d_in, const int* in_sizes, int n_in,
                              void* d_out, int out_size, void* d_ws, size_t ws_size,
                              hipStream_t stream) {
    (void)in_sizes; (void)n_in; (void)out_size;
    const float* x  = (const float*)d_in[0];
    const float* A1 = (const float*)d_in[1];
    const float* A2 = (const float*)d_in[2];
    const float* W  = (const float*)d_in[3];
    const float* bs = (const float*)d_in[4];
    float* y = (float*)d_out;
    char* ws = (char*)d_ws;

    // workspace layout:
    //   [0, 33554432)            Astack bf16 [8192][2048]  (A1, A1^2, A2, A2^2)
    //   [33554432, 33595392)     Wbf bf16 [5][64][64]
    //   [33619968, ...)          chunk region: A1T/A2T (transient), then XtT + Y per chunk
    const size_t CHUNK_OFF = 33619968;
    u16* astack = (u16*)ws;
    u16* wbf = (u16*)(ws + 33554432);
    u16* a1t = (u16*)(ws + CHUNK_OFF);
    u16* a2t = a1t + (size_t)2048 * 2048;

    // adaptive chunking over batch dim (Gb batches per chunk); per-chunk bytes =
    // XtT (Gb*3145728) + Y (Gb*12582912)
    size_t avail = ws_size > CHUNK_OFF ? ws_size - CHUNK_OFF : 0;
    int Gb = 16;
    while (Gb > 1 && (size_t)Gb * 15728640 > avail) Gb >>= 1;
    u16* xtT = (u16*)(ws + CHUNK_OFF);
    u16* Yb = xtT + (size_t)Gb * 768 * 2048;
    int ldy = Gb * 768;
    int nPerBlk = 16 / Gb;

    cvt_w_kernel<<<80, 256, 0, stream>>>(W, wbf);
    cvt_a_kernel<<<2048, 256, 0, stream>>>(A1, A2, astack, a1t, a2t);

    // A1^2 and A2^2 (one dual launch, 512 blocks)
    gemm_bt_kernel<<<dim3(16, 16, 2), 256, 0, stream>>>(
        astack, a1t, astack + (size_t)2048 * 2048,
        astack + (size_t)4096 * 2048, a2t, astack + (size_t)6144 * 2048,
        2048, 2048, 2048, 2048);

    for (int b0 = 0; b0 < 16; b0 += Gb) {
        pack_x_kernel<<<Gb * 512, 256, 0, stream>>>(x, xtT, b0, Gb);
        gemm_bt_kernel<<<dim3(Gb * 6, 64, 1), 256, 0, stream>>>(
            astack, xtT, Yb, astack, xtT, Yb,
            2048, 2048, 2048, ldy);
        conv_kernel<<<128 * Gb, 256, 0, stream>>>(x, Yb, wbf, bs, y, b0, Gb, nPerBlk, ldy);
    }
}

// Round 2
// 634.771 us; speedup vs baseline: 1.1495x; 1.1495x over previous
//
#include <hip/hip_runtime.h>

// SparseGraphConv: y = W @ concat([x, A1x, A1^2 x, A2 x, A2^2 x]) + b
// B=16, C=64, N=2048, T=12, C_OUT=64.
//
// Strategy:
//   1. cvt_a:   A1,A2 f32 -> bf16 rows of Astack[8192,2048] (+ transposed copies for A^2 GEMM)
//   2. gemm128(z=2): A1^2, A2^2 -> remaining Astack rows
//   3. pack_x:  x[b,c,n,t] f32 -> XtT[(b*12+t)*64+c][n] bf16
//   4. gemm256: Y[8192, 12288] = Astack @ XtT^T  -- 8-phase 256^2 schedule (T2+T3+T4+T5)
//   5. conv:    per node n: y[b,o,n,t] = bias[o] + sum_k W_k @ h_k

typedef __attribute__((ext_vector_type(8))) __bf16 bf16x8;
typedef __attribute__((ext_vector_type(4))) float f32x4;
typedef __attribute__((ext_vector_type(8))) unsigned short u16x8;
typedef unsigned short u16;
typedef unsigned int u32;

__device__ __forceinline__ u16 f2bf(float f) {
    u32 u = __float_as_uint(f);
    u32 r = u + 0x7FFFu + ((u >> 16) & 1u);   // round-to-nearest-even
    return (u16)(r >> 16);
}

__device__ __forceinline__ void gload16(const void* g, void* l) {
    __builtin_amdgcn_global_load_lds((const __attribute__((address_space(1))) void*)g,
                                     (__attribute__((address_space(3))) void*)l, 16, 0, 0);
}

// ---------------------------------------------------------------------------
__global__ __launch_bounds__(256)
void cvt_w_kernel(const float* __restrict__ W, u16* __restrict__ wbf) {
    int i = blockIdx.x * 256 + threadIdx.x;
    if (i < 5 * 64 * 64) {
        int c = i & 63;
        int o = (i >> 6) & 63;
        int k = i >> 12;
        wbf[i] = f2bf(W[o * 320 + k * 64 + c]);
    }
}

// ---------------------------------------------------------------------------
__global__ __launch_bounds__(256)
void cvt_a_kernel(const float* __restrict__ A1, const float* __restrict__ A2,
                  u16* __restrict__ astack, u16* __restrict__ a1t, u16* __restrict__ a2t) {
    __shared__ float lt[64][65];
    int bid = blockIdx.x;
    int mat = bid >> 10;
    int ti = bid & 1023;
    int tr = (ti >> 5) << 6;
    int tc = (ti & 31) << 6;
    const float* src = mat ? A2 : A1;
    u16* dstA = astack + (size_t)(mat ? 4096 : 0) * 2048;
    u16* dstT = mat ? a2t : a1t;
    int tid = threadIdx.x;
    int rr = tid >> 4;
    int cc = (tid & 15) << 2;
#pragma unroll
    for (int p = 0; p < 4; ++p) {
        int row = p * 16 + rr;
        float4 v = *(const float4*)&src[(size_t)(tr + row) * 2048 + tc + cc];
        ushort4 o;
        o.x = f2bf(v.x); o.y = f2bf(v.y); o.z = f2bf(v.z); o.w = f2bf(v.w);
        *(ushort4*)&dstA[(size_t)(tr + row) * 2048 + tc + cc] = o;
        lt[row][cc + 0] = v.x; lt[row][cc + 1] = v.y;
        lt[row][cc + 2] = v.z; lt[row][cc + 3] = v.w;
    }
    __syncthreads();
#pragma unroll
    for (int p = 0; p < 4; ++p) {
        int row = p * 16 + rr;
        ushort4 o;
        o.x = f2bf(lt[cc + 0][row]); o.y = f2bf(lt[cc + 1][row]);
        o.z = f2bf(lt[cc + 2][row]); o.w = f2bf(lt[cc + 3][row]);
        *(ushort4*)&dstT[(size_t)(tc + row) * 2048 + tr + cc] = o;
    }
}

// ---------------------------------------------------------------------------
__global__ __launch_bounds__(256)
void pack_x_kernel(const float* __restrict__ x, u16* __restrict__ XtT, int b0, int Gb) {
    int tid = blockIdx.x * 256 + threadIdx.x;
    int n = tid & 2047;
    int bc = tid >> 11;
    int c = bc & 63;
    int bl = bc >> 6;
    const float* src = x + ((size_t)((b0 + bl) * 64 + c) * 2048 + n) * 12;
    float4 v0 = *(const float4*)(src + 0);
    float4 v1 = *(const float4*)(src + 4);
    float4 v2 = *(const float4*)(src + 8);
    float vv[12];
    *(float4*)&vv[0] = v0; *(float4*)&vv[4] = v1; *(float4*)&vv[8] = v2;
    u16* dst = XtT + (size_t)(bl * 12 * 64 + c) * 2048 + n;
#pragma unroll
    for (int t = 0; t < 12; ++t)
        dst[(size_t)t * 64 * 2048] = f2bf(vv[t]);
}

// ---------------------------------------------------------------------------
// 128^2-tile GEMM (kept for the small A^2 GEMMs; 512-block grid there).
__global__ __launch_bounds__(256, 2)
void gemm_bt_kernel(const u16* __restrict__ A0, const u16* __restrict__ B0, u16* __restrict__ C0,
                    const u16* __restrict__ A1p, const u16* __restrict__ B1p, u16* __restrict__ C1p,
                    int K, int lda, int ldb, int ldc) {
    const u16* A  = blockIdx.z ? A1p : A0;
    const u16* BT = blockIdx.z ? B1p : B0;
    u16* C        = blockIdx.z ? C1p : C0;

    __shared__ u16 lA[128 * 64];
    __shared__ u16 lB[128 * 64];

    int gx = gridDim.x;
    int nwg = gx * gridDim.y;
    int orig = blockIdx.y * gx + blockIdx.x;
    int swz = (orig & 7) * (nwg >> 3) + (orig >> 3);
    int by = swz / gx, bx = swz - by * gx;

    const int m0 = by * 128, n0 = bx * 128;
    const int tid = threadIdx.x;
    const int w = tid >> 6, l = tid & 63;
    const int wr = w >> 1, wc = w & 1;

    f32x4 acc[4][4] = {};

    const int srow = l >> 3;
    const int scol = ((l & 7) ^ srow) * 8;

    for (int kt = 0; kt < K; kt += 64) {
#pragma unroll
        for (int r = 0; r < 4; ++r) {
            int s = w * 4 + r;
            int row = s * 8 + srow;
            gload16(A + (size_t)(m0 + row) * lda + kt + scol, &lA[s * 512]);
        }
#pragma unroll
        for (int r = 0; r < 4; ++r) {
            int s = w * 4 + r;
            int row = s * 8 + srow;
            gload16(BT + (size_t)(n0 + row) * ldb + kt + scol, &lB[s * 512]);
        }
        __syncthreads();
#pragma unroll
        for (int kk = 0; kk < 2; ++kk) {
            bf16x8 af[4], bfr[4];
            const int cg = ((kk * 4 + (l >> 4)) ^ (l & 7)) * 8;
#pragma unroll
            for (int i = 0; i < 4; ++i)
                af[i] = *(const bf16x8*)&lA[(wr * 64 + i * 16 + (l & 15)) * 64 + cg];
#pragma unroll
            for (int j = 0; j < 4; ++j)
                bfr[j] = *(const bf16x8*)&lB[(wc * 64 + j * 16 + (l & 15)) * 64 + cg];
#pragma unroll
            for (int i = 0; i < 4; ++i)
#pragma unroll
                for (int j = 0; j < 4; ++j)
                    acc[i][j] = __builtin_amdgcn_mfma_f32_16x16x32_bf16(af[i], bfr[j], acc[i][j], 0, 0, 0);
        }
        __syncthreads();
    }

    const int lr = (l >> 4) * 4, lc = l & 15;
#pragma unroll
    for (int i = 0; i < 4; ++i) {
        int row = m0 + wr * 64 + i * 16 + lr;
#pragma unroll
        for (int j = 0; j < 4; ++j) {
            int col = n0 + wc * 64 + j * 16 + lc;
            u16* p = C + (size_t)row * ldc + col;
#pragma unroll
            for (int q = 0; q < 4; ++q)
                p[(size_t)q * ldc] = f2bf(acc[i][j][q]);
        }
    }
}

// ---------------------------------------------------------------------------
// 256^2-tile 8-phase GEMM (T2 swizzle + T3/T4 counted-vmcnt pipeline + T5 setprio).
// C[M,N] = A[M,K] @ BT[N,K]^T, bf16 in, bf16 out, f32 accum.
// 512 thr / 8 waves (2Mx4N), per-wave 128x64 out, BK=64, LDS 128 KiB (2 dbuf).
//
// Pipeline (race-free by construction):
//   tile T -> buf[T&1]. Stages of tile T+1: halves {A0,A1,B0} issued at the
//   end-of-(T-1) boundary (right after all reads of buf[(T+1)&1] are provably
//   drained by the phase-3 trailing barrier of tile T-1), half {B1} in T's
//   phase 1. Boundary does vmcnt(6) (3 half-tiles in flight) + barrier;
//   vmcnt(6) guarantees everything older than the newest 3 halves has landed,
//   which includes ALL of tile T+1's 8 issues.
__device__ __forceinline__ void stage_half256(const u16* __restrict__ src, int ld,
                                              u16* lds, int kt, int tid) {
    int w8 = (tid >> 6) << 3;      // wave*8 rows
    int l = tid & 63;
    int r = l >> 3;                // row within 8-row stripe
#pragma unroll
    for (int iss = 0; iss < 2; ++iss) {
        int R = iss * 64 + w8 + r;
        gload16(src + (size_t)R * ld + kt + (((l & 7) ^ r) << 3),
                lds + (size_t)(iss * 64 + w8) * 64);
    }
}

__global__ __launch_bounds__(512, 2)
void gemm256_kernel(const u16* __restrict__ A, const u16* __restrict__ BT,
                    u16* __restrict__ C, int K, int lda, int ldb, int ldc) {
    __shared__ u16 lds[2][2][256 * 64];   // [buf][A=0/B=1][row*64+col] : 128 KiB

    int gx = gridDim.x;
    int nwg = gx * gridDim.y;
    int orig = blockIdx.y * gx + blockIdx.x;
    int swz = (orig & 7) * (nwg >> 3) + (orig >> 3);
    int by = swz / gx, bx = swz - by * gx;

    const int m0 = by * 256, n0 = bx * 256;
    const int tid = threadIdx.x;
    const int w = tid >> 6, l = tid & 63;
    const int wr = w >> 2, wc = w & 3;      // 2 x 4 wave grid
    const int NT = K >> 6;

    f32x4 acc[2][2][4][2] = {};             // [qm][qn][i][j]

    // prologue: tile 0 (4 halves) -> buf0; tile 1 halves {A0,A1,B0} -> buf1
    {
#pragma unroll
        for (int h = 0; h < 2; ++h)
            stage_half256(A + (size_t)(m0 + h * 128) * lda, lda, &lds[0][0][h * 128 * 64], 0, tid);
#pragma unroll
        for (int h = 0; h < 2; ++h)
            stage_half256(BT + (size_t)(n0 + h * 128) * ldb, ldb, &lds[0][1][h * 128 * 64], 0, tid);
        if (NT > 1) {
            stage_half256(A + (size_t)m0 * lda, lda, &lds[1][0][0], 64, tid);
            stage_half256(A + (size_t)(m0 + 128) * lda, lda, &lds[1][0][128 * 64], 64, tid);
            stage_half256(BT + (size_t)n0 * ldb, ldb, &lds[1][1][0], 64, tid);
            asm volatile("s_waitcnt vmcnt(6)" ::: "memory");
        } else {
            asm volatile("s_waitcnt vmcnt(0)" ::: "memory");
        }
        __builtin_amdgcn_s_barrier();
    }

    bf16x8 af[2][4];      // current qm A-frags [kk][i]
    bf16x8 bq0[2][2];     // qn=0 B-frags [kk][j]
    bf16x8 bq1[2][2];     // qn=1 B-frags

    for (int t = 0; t < NT; ++t) {
        const int cur = t & 1;
        const u16* lA = lds[cur][0];
        const u16* lB = lds[cur][1];

        // ---- phase 1: reads A(qm0) + B(qn0); stage t+1 half B1 ----
#pragma unroll
        for (int kk = 0; kk < 2; ++kk) {
#pragma unroll
            for (int i = 0; i < 4; ++i) {
                int r = wr * 128 + i * 16 + (l & 15);
                int g = kk * 4 + (l >> 4);
                af[kk][i] = *(const bf16x8*)&lA[(size_t)r * 64 + ((g ^ (r & 7)) << 3)];
            }
#pragma unroll
            for (int j = 0; j < 2; ++j) {
                int r = wc * 64 + j * 16 + (l & 15);
                int g = kk * 4 + (l >> 4);
                bq0[kk][j] = *(const bf16x8*)&lB[(size_t)r * 64 + ((g ^ (r & 7)) << 3)];
            }
        }
        if (t + 1 < NT)
            stage_half256(BT + (size_t)(n0 + 128) * ldb, ldb, &lds[cur ^ 1][1][128 * 64],
                          (t + 1) << 6, tid);
        __builtin_amdgcn_s_barrier();
        __builtin_amdgcn_s_setprio(1);
#pragma unroll
        for (int kk = 0; kk < 2; ++kk)
#pragma unroll
            for (int i = 0; i < 4; ++i)
#pragma unroll
                for (int j = 0; j < 2; ++j)
                    acc[0][0][i][j] = __builtin_amdgcn_mfma_f32_16x16x32_bf16(af[kk][i], bq0[kk][j], acc[0][0][i][j], 0, 0, 0);
        __builtin_amdgcn_s_setprio(0);
        __builtin_amdgcn_s_barrier();

        // ---- phase 2: reads B(qn1) ----
#pragma unroll
        for (int kk = 0; kk < 2; ++kk)
#pragma unroll
            for (int j = 0; j < 2; ++j) {
                int r = wc * 64 + 32 + j * 16 + (l & 15);
                int g = kk * 4 + (l >> 4);
                bq1[kk][j] = *(const bf16x8*)&lB[(size_t)r * 64 + ((g ^ (r & 7)) << 3)];
            }
        __builtin_amdgcn_s_barrier();
        __builtin_amdgcn_s_setprio(1);
#pragma unroll
        for (int kk = 0; kk < 2; ++kk)
#pragma unroll
            for (int i = 0; i < 4; ++i)
#pragma unroll
                for (int j = 0; j < 2; ++j)
                    acc[0][1][i][j] = __builtin_amdgcn_mfma_f32_16x16x32_bf16(af[kk][i], bq1[kk][j], acc[0][1][i][j], 0, 0, 0);
        __builtin_amdgcn_s_setprio(0);
        __builtin_amdgcn_s_barrier();

        // ---- phase 3: reads A(qm1) ----
#pragma unroll
        for (int kk = 0; kk < 2; ++kk)
#pragma unroll
            for (int i = 0; i < 4; ++i) {
                int r = wr * 128 + 64 + i * 16 + (l & 15);
                int g = kk * 4 + (l >> 4);
                af[kk][i] = *(const bf16x8*)&lA[(size_t)r * 64 + ((g ^ (r & 7)) << 3)];
            }
        __builtin_amdgcn_s_barrier();
        __builtin_amdgcn_s_setprio(1);
#pragma unroll
        for (int kk = 0; kk < 2; ++kk)
#pragma unroll
            for (int i = 0; i < 4; ++i)
#pragma unroll
                for (int j = 0; j < 2; ++j)
                    acc[1][0][i][j] = __builtin_amdgcn_mfma_f32_16x16x32_bf16(af[kk][i], bq0[kk][j], acc[1][0][i][j], 0, 0, 0);
        __builtin_amdgcn_s_setprio(0);
        __builtin_amdgcn_s_barrier();

        // ---- phase 4: no reads; MFMA q11; boundary for tile t+1 ----
        __builtin_amdgcn_s_setprio(1);
#pragma unroll
        for (int kk = 0; kk < 2; ++kk)
#pragma unroll
            for (int i = 0; i < 4; ++i)
#pragma unroll
                for (int j = 0; j < 2; ++j)
                    acc[1][1][i][j] = __builtin_amdgcn_mfma_f32_16x16x32_bf16(af[kk][i], bq1[kk][j], acc[1][1][i][j], 0, 0, 0);
        __builtin_amdgcn_s_setprio(0);

        if (t + 1 < NT) {
            if (t + 2 < NT) {
                // stages of t+2 -> buf[cur]: all reads of buf[cur] drained at
                // phase-3 trailing barrier above.
                int kt2 = (t + 2) << 6;
                stage_half256(A + (size_t)m0 * lda, lda, &lds[cur][0][0], kt2, tid);
                stage_half256(A + (size_t)(m0 + 128) * lda, lda, &lds[cur][0][128 * 64], kt2, tid);
                stage_half256(BT + (size_t)n0 * ldb, ldb, &lds[cur][1][0], kt2, tid);
                asm volatile("s_waitcnt vmcnt(6)" ::: "memory");
            } else {
                asm volatile("s_waitcnt vmcnt(0)" ::: "memory");
            }
            __builtin_amdgcn_s_barrier();
        }
    }

    // C/D layout: col = lane&15, row = (lane>>4)*4 + reg
    const int lr = (l >> 4) * 4, lc = l & 15;
#pragma unroll
    for (int qm = 0; qm < 2; ++qm)
#pragma unroll
        for (int i = 0; i < 4; ++i) {
            int row = m0 + wr * 128 + qm * 64 + i * 16 + lr;
#pragma unroll
            for (int qn = 0; qn < 2; ++qn)
#pragma unroll
                for (int j = 0; j < 2; ++j) {
                    int col = n0 + wc * 64 + qn * 32 + j * 16 + lc;
                    u16* p = C + (size_t)row * ldc + col;
#pragma unroll
                    for (int q = 0; q < 4; ++q)
                        p[(size_t)q * ldc] = f2bf(acc[qm][qn][i][j][q]);
                }
        }
}

// ---------------------------------------------------------------------------
__global__ __launch_bounds__(256, 2)
void conv_kernel(const float* __restrict__ x, const u16* __restrict__ Y,
                 const u16* __restrict__ Wbf, const float* __restrict__ bias,
                 float* __restrict__ yout, int b0, int Gb, int nPerBlk, int ldy) {
    __shared__ u16 lh[192 * 72];
    const int colsPerN = Gb * 12;
    const int n0 = blockIdx.x * nPerBlk;
    const int tid = threadIdx.x;
    const int w = tid >> 6, l = tid & 63;
    f32x4 acc[4][3] = {};

    for (int k = 0; k < 5; ++k) {
        __syncthreads();
        if (k == 0) {
            const int tot = nPerBlk * Gb * 64;
            for (int it = tid; it < tot; it += 256) {
                int c = it & 63;
                int bn = it >> 6;
                int bl = bn % Gb;
                int nl = bn / Gb;
                const float* src = x + ((size_t)((b0 + bl) * 64 + c) * 2048 + (n0 + nl)) * 12;
                float4 v0 = *(const float4*)(src + 0);
                float4 v1 = *(const float4*)(src + 4);
                float4 v2 = *(const float4*)(src + 8);
                float vv[12];
                *(float4*)&vv[0] = v0; *(float4*)&vv[4] = v1; *(float4*)&vv[8] = v2;
                u16* d = &lh[(nl * colsPerN + bl * 12) * 72 + c];
#pragma unroll
                for (int t = 0; t < 12; ++t) d[t * 72] = f2bf(vv[t]);
            }
        } else {
            for (int it = tid; it < 1536; it += 256) {
                int e8 = it << 3;
                int c = e8 & 63;
                int jj = e8 >> 6;
                int nl = jj / colsPerN;
                int rem = jj - nl * colsPerN;
                const u16* src = Y + (size_t)((k - 1) * 2048 + n0 + nl) * ldy + rem * 64 + c;
                *(u16x8*)&lh[jj * 72 + c] = *(const u16x8*)src;
            }
        }
        __syncthreads();
#pragma unroll
        for (int kk = 0; kk < 2; ++kk) {
            bf16x8 wf[4], hf[3];
#pragma unroll
            for (int i = 0; i < 4; ++i)
                wf[i] = *(const bf16x8*)&Wbf[(size_t)(k * 64 + i * 16 + (l & 15)) * 64 + kk * 32 + (l >> 4) * 8];
#pragma unroll
            for (int j = 0; j < 3; ++j)
                hf[j] = *(const bf16x8*)&lh[(w * 48 + j * 16 + (l & 15)) * 72 + kk * 32 + (l >> 4) * 8];
#pragma unroll
            for (int i = 0; i < 4; ++i)
#pragma unroll
                for (int j = 0; j < 3; ++j)
                    acc[i][j] = __builtin_amdgcn_mfma_f32_16x16x32_bf16(wf[i], hf[j], acc[i][j], 0, 0, 0);
        }
    }

    const int lr = (l >> 4) * 4, lc = l & 15;
#pragma unroll
    for (int j = 0; j < 3; ++j) {
        int jj = w * 48 + j * 16 + lc;
        int nl = jj / colsPerN;
        int rem = jj - nl * colsPerN;
        int bl = rem / 12;
        int t = rem - bl * 12;
#pragma unroll
        for (int i = 0; i < 4; ++i) {
#pragma unroll
            for (int q = 0; q < 4; ++q) {
                int o = i * 16 + lr + q;
                yout[((size_t)((b0 + bl) * 64 + o) * 2048 + (n0 + nl)) * 12 + t] = acc[i][j][q] + bias[o];
            }
        }
    }
}

// ---------------------------------------------------------------------------
extern "C" void kernel_launch(void* const* d_in, const int* in_sizes, int n_in,
                              void* d_out, int out_size, void* d_ws, size_t ws_size,
                              hipStream_t stream) {
    (void)in_sizes; (void)n_in; (void)out_size;
    const float* x  = (const float*)d_in[0];
    const float* A1 = (const float*)d_in[1];
    const float* A2 = (const float*)d_in[2];
    const float* W  = (const float*)d_in[3];
    const float* bs = (const float*)d_in[4];
    float* y = (float*)d_out;
    char* ws = (char*)d_ws;

    const size_t CHUNK_OFF = 33619968;
    u16* astack = (u16*)ws;
    u16* wbf = (u16*)(ws + 33554432);
    u16* a1t = (u16*)(ws + CHUNK_OFF);
    u16* a2t = a1t + (size_t)2048 * 2048;

    size_t avail = ws_size > CHUNK_OFF ? ws_size - CHUNK_OFF : 0;
    int Gb = 16;
    while (Gb > 1 && (size_t)Gb * 15728640 > avail) Gb >>= 1;
    u16* xtT = (u16*)(ws + CHUNK_OFF);
    u16* Yb = xtT + (size_t)Gb * 768 * 2048;
    int ldy = Gb * 768;
    int nPerBlk = 16 / Gb;

    cvt_w_kernel<<<80, 256, 0, stream>>>(W, wbf);
    cvt_a_kernel<<<2048, 256, 0, stream>>>(A1, A2, astack, a1t, a2t);

    gemm_bt_kernel<<<dim3(16, 16, 2), 256, 0, stream>>>(
        astack, a1t, astack + (size_t)2048 * 2048,
        astack + (size_t)4096 * 2048, a2t, astack + (size_t)6144 * 2048,
        2048, 2048, 2048, 2048);

    for (int b0 = 0; b0 < 16; b0 += Gb) {
        pack_x_kernel<<<Gb * 512, 256, 0, stream>>>(x, xtT, b0, Gb);
        gemm256_kernel<<<dim3(ldy / 256, 32), 512, 0, stream>>>(
            astack, xtT, Yb, 2048, 2048, 2048, ldy);
        conv_kernel<<<128 * Gb, 256, 0, stream>>>(x, Yb, wbf, bs, y, b0, Gb, nPerBlk, ldy);
    }
}

// Round 4
// 623.546 us; speedup vs baseline: 1.1702x; 1.0180x over previous
//
#include <hip/hip_runtime.h>

// SparseGraphConv: y = W @ concat([x, A1x, A1^2 x, A2 x, A2^2 x]) + b
// B=16, C=64, N=2048, T=12, C_OUT=64.
//
//   1. cvt_a:   A1,A2 f32 -> bf16 rows of Astack[8192,2048] (+ transposed copies)
//   2. gemm128(z=2): A1^2, A2^2 -> remaining Astack rows
//   3. pack_x:  x[b,c,n,t] f32 -> XtT[(b*12+t)*64+c][n] bf16
//   4. gemm256: Y[8192, 12288] = Astack @ XtT^T  -- 256^2, R2 sync skeleton,
//               stages spread across phases (m196 fine interleave)
//   5. conv:    per node n: y[b,o,n,t] = bias[o] + sum_k W_k @ h_k

typedef __attribute__((ext_vector_type(8))) __bf16 bf16x8;
typedef __attribute__((ext_vector_type(4))) float f32x4;
typedef __attribute__((ext_vector_type(8))) unsigned short u16x8;
typedef unsigned short u16;
typedef unsigned int u32;

__device__ __forceinline__ u16 f2bf(float f) {
    u32 u = __float_as_uint(f);
    u32 r = u + 0x7FFFu + ((u >> 16) & 1u);   // round-to-nearest-even
    return (u16)(r >> 16);
}

__device__ __forceinline__ void gload16(const void* g, void* l) {
    __builtin_amdgcn_global_load_lds((const __attribute__((address_space(1))) void*)g,
                                     (__attribute__((address_space(3))) void*)l, 16, 0, 0);
}

// ---------------------------------------------------------------------------
__global__ __launch_bounds__(256)
void cvt_w_kernel(const float* __restrict__ W, u16* __restrict__ wbf) {
    int i = blockIdx.x * 256 + threadIdx.x;
    if (i < 5 * 64 * 64) {
        int c = i & 63;
        int o = (i >> 6) & 63;
        int k = i >> 12;
        wbf[i] = f2bf(W[o * 320 + k * 64 + c]);
    }
}

// ---------------------------------------------------------------------------
__global__ __launch_bounds__(256)
void cvt_a_kernel(const float* __restrict__ A1, const float* __restrict__ A2,
                  u16* __restrict__ astack, u16* __restrict__ a1t, u16* __restrict__ a2t) {
    __shared__ float lt[64][65];
    int bid = blockIdx.x;
    int mat = bid >> 10;
    int ti = bid & 1023;
    int tr = (ti >> 5) << 6;
    int tc = (ti & 31) << 6;
    const float* src = mat ? A2 : A1;
    u16* dstA = astack + (size_t)(mat ? 4096 : 0) * 2048;
    u16* dstT = mat ? a2t : a1t;
    int tid = threadIdx.x;
    int rr = tid >> 4;
    int cc = (tid & 15) << 2;
#pragma unroll
    for (int p = 0; p < 4; ++p) {
        int row = p * 16 + rr;
        float4 v = *(const float4*)&src[(size_t)(tr + row) * 2048 + tc + cc];
        ushort4 o;
        o.x = f2bf(v.x); o.y = f2bf(v.y); o.z = f2bf(v.z); o.w = f2bf(v.w);
        *(ushort4*)&dstA[(size_t)(tr + row) * 2048 + tc + cc] = o;
        lt[row][cc + 0] = v.x; lt[row][cc + 1] = v.y;
        lt[row][cc + 2] = v.z; lt[row][cc + 3] = v.w;
    }
    __syncthreads();
#pragma unroll
    for (int p = 0; p < 4; ++p) {
        int row = p * 16 + rr;
        ushort4 o;
        o.x = f2bf(lt[cc + 0][row]); o.y = f2bf(lt[cc + 1][row]);
        o.z = f2bf(lt[cc + 2][row]); o.w = f2bf(lt[cc + 3][row]);
        *(ushort4*)&dstT[(size_t)(tc + row) * 2048 + tr + cc] = o;
    }
}

// ---------------------------------------------------------------------------
__global__ __launch_bounds__(256)
void pack_x_kernel(const float* __restrict__ x, u16* __restrict__ XtT, int b0, int Gb) {
    int tid = blockIdx.x * 256 + threadIdx.x;
    int n = tid & 2047;
    int bc = tid >> 11;
    int c = bc & 63;
    int bl = bc >> 6;
    const float* src = x + ((size_t)((b0 + bl) * 64 + c) * 2048 + n) * 12;
    float4 v0 = *(const float4*)(src + 0);
    float4 v1 = *(const float4*)(src + 4);
    float4 v2 = *(const float4*)(src + 8);
    float vv[12];
    *(float4*)&vv[0] = v0; *(float4*)&vv[4] = v1; *(float4*)&vv[8] = v2;
    u16* dst = XtT + (size_t)(bl * 12 * 64 + c) * 2048 + n;
#pragma unroll
    for (int t = 0; t < 12; ++t)
        dst[(size_t)t * 64 * 2048] = f2bf(vv[t]);
}

// ---------------------------------------------------------------------------
// 128^2-tile GEMM (kept for the small A^2 GEMMs).
__global__ __launch_bounds__(256, 2)
void gemm_bt_kernel(const u16* __restrict__ A0, const u16* __restrict__ B0, u16* __restrict__ C0,
                    const u16* __restrict__ A1p, const u16* __restrict__ B1p, u16* __restrict__ C1p,
                    int K, int lda, int ldb, int ldc) {
    const u16* A  = blockIdx.z ? A1p : A0;
    const u16* BT = blockIdx.z ? B1p : B0;
    u16* C        = blockIdx.z ? C1p : C0;

    __shared__ u16 lA[128 * 64];
    __shared__ u16 lB[128 * 64];

    int gx = gridDim.x;
    int nwg = gx * gridDim.y;
    int orig = blockIdx.y * gx + blockIdx.x;
    int swz = (orig & 7) * (nwg >> 3) + (orig >> 3);
    int by = swz / gx, bx = swz - by * gx;

    const int m0 = by * 128, n0 = bx * 128;
    const int tid = threadIdx.x;
    const int w = tid >> 6, l = tid & 63;
    const int wr = w >> 1, wc = w & 1;

    f32x4 acc[4][4] = {};

    const int srow = l >> 3;
    const int scol = ((l & 7) ^ srow) * 8;

    for (int kt = 0; kt < K; kt += 64) {
#pragma unroll
        for (int r = 0; r < 4; ++r) {
            int s = w * 4 + r;
            int row = s * 8 + srow;
            gload16(A + (size_t)(m0 + row) * lda + kt + scol, &lA[s * 512]);
        }
#pragma unroll
        for (int r = 0; r < 4; ++r) {
            int s = w * 4 + r;
            int row = s * 8 + srow;
            gload16(BT + (size_t)(n0 + row) * ldb + kt + scol, &lB[s * 512]);
        }
        __syncthreads();
#pragma unroll
        for (int kk = 0; kk < 2; ++kk) {
            bf16x8 af[4], bfr[4];
            const int cg = ((kk * 4 + (l >> 4)) ^ (l & 7)) * 8;
#pragma unroll
            for (int i = 0; i < 4; ++i)
                af[i] = *(const bf16x8*)&lA[(wr * 64 + i * 16 + (l & 15)) * 64 + cg];
#pragma unroll
            for (int j = 0; j < 4; ++j)
                bfr[j] = *(const bf16x8*)&lB[(wc * 64 + j * 16 + (l & 15)) * 64 + cg];
#pragma unroll
            for (int i = 0; i < 4; ++i)
#pragma unroll
                for (int j = 0; j < 4; ++j)
                    acc[i][j] = __builtin_amdgcn_mfma_f32_16x16x32_bf16(af[i], bfr[j], acc[i][j], 0, 0, 0);
        }
        __syncthreads();
    }

    const int lr = (l >> 4) * 4, lc = l & 15;
#pragma unroll
    for (int i = 0; i < 4; ++i) {
        int row = m0 + wr * 64 + i * 16 + lr;
#pragma unroll
        for (int j = 0; j < 4; ++j) {
            int col = n0 + wc * 64 + j * 16 + lc;
            u16* p = C + (size_t)row * ldc + col;
#pragma unroll
            for (int q = 0; q < 4; ++q)
                p[(size_t)q * ldc] = f2bf(acc[i][j][q]);
        }
    }
}

// ---------------------------------------------------------------------------
// 256^2-tile GEMM. R2's verified sync skeleton (8 waves, 2 dbuf, single
// vmcnt(6)+barrier boundary per tile), with the stage issues SPREAD across
// phases: B1(t+1)@P1 -> buf^1; A0(t+2)@P2, B0(t+2)@P3, A1(t+2)@P4 -> buf cur.
//
// Drain ledger (steady, per wave; stage = 2 loads):
//   at P4(t) vmcnt(6): outstanding = t+2{A0,B0,A1}(6) + B1(t+1)(2) -> drains
//   B1(t+1) and everything older (= all of tile t+1), published at boundary
//   barrier. Reads of tile t+1 happen in the 4 phases after that barrier.
// Overwrite safety (stage into buf-cur while reading it):
//   A-half0 ds_reads end in P1, staged in P2 (1 barrier later);
//   B-half0 ds_reads end in P1, staged in P3;
//   A-half1 ds_reads end in P3, staged in P4 (after P3-end barrier);
//   B-half1 of buf^1 last read in tile t-1's P2, staged in P1(t).
__device__ __forceinline__ void stage_half256(const u16* __restrict__ src, int ld,
                                              u16* lds, int kt, int tid) {
    int w8 = (tid >> 6) << 3;
    int l = tid & 63;
    int r = l >> 3;
#pragma unroll
    for (int iss = 0; iss < 2; ++iss) {
        int R = iss * 64 + w8 + r;
        gload16(src + (size_t)R * ld + kt + (((l & 7) ^ r) << 3),
                lds + (size_t)(iss * 64 + w8) * 64);
    }
}

__global__ __launch_bounds__(512, 2)
void gemm256_kernel(const u16* __restrict__ A, const u16* __restrict__ BT,
                    u16* __restrict__ C, int K, int lda, int ldb, int ldc) {
    __shared__ u16 lds[2][2][256 * 64];   // [buf][A=0/B=1] : 128 KiB

    int gx = gridDim.x;
    int nwg = gx * gridDim.y;
    int orig = blockIdx.y * gx + blockIdx.x;
    int swz = (orig & 7) * (nwg >> 3) + (orig >> 3);
    int by = swz / gx, bx = swz - by * gx;

    const int m0 = by * 256, n0 = bx * 256;
    const int tid = threadIdx.x;
    const int w = tid >> 6, l = tid & 63;
    const int wr = w >> 2, wc = w & 3;      // 2 x 4 wave grid
    const int NT = K >> 6;

    f32x4 acc[2][2][4][2] = {};             // [qm][qn][i][j]

    // prologue: tile 0 (4 halves) -> buf0; tile 1 halves {A0,A1,B0} -> buf1
    {
#pragma unroll
        for (int h = 0; h < 2; ++h)
            stage_half256(A + (size_t)(m0 + h * 128) * lda, lda, &lds[0][0][h * 128 * 64], 0, tid);
#pragma unroll
        for (int h = 0; h < 2; ++h)
            stage_half256(BT + (size_t)(n0 + h * 128) * ldb, ldb, &lds[0][1][h * 128 * 64], 0, tid);
        if (NT > 1) {
            stage_half256(A + (size_t)m0 * lda, lda, &lds[1][0][0], 64, tid);
            stage_half256(A + (size_t)(m0 + 128) * lda, lda, &lds[1][0][128 * 64], 64, tid);
            stage_half256(BT + (size_t)n0 * ldb, ldb, &lds[1][1][0], 64, tid);
            asm volatile("s_waitcnt vmcnt(6)" ::: "memory");
        } else {
            asm volatile("s_waitcnt vmcnt(0)" ::: "memory");
        }
        __builtin_amdgcn_s_barrier();
    }

    bf16x8 af[2][4];      // current qm A-frags [kk][i]
    bf16x8 bq0[2][2];     // qn=0 B-frags [kk][j]
    bf16x8 bq1[2][2];     // qn=1 B-frags

    for (int t = 0; t < NT; ++t) {
        const int cur = t & 1;
        u16* lA = lds[cur][0];
        u16* lB = lds[cur][1];
        const bool s1 = (t + 1 < NT);
        const bool s2 = (t + 2 < NT);
        const int kt1 = (t + 1) << 6;
        const int kt2 = (t + 2) << 6;

        // ---- phase 1: reads A(qm0) + B(qn0); stage B1(t+1) -> buf^1 ----
#pragma unroll
        for (int kk = 0; kk < 2; ++kk) {
#pragma unroll
            for (int i = 0; i < 4; ++i) {
                int r = wr * 128 + i * 16 + (l & 15);
                int g = kk * 4 + (l >> 4);
                af[kk][i] = *(const bf16x8*)&lA[(size_t)r * 64 + ((g ^ (r & 7)) << 3)];
            }
#pragma unroll
            for (int j = 0; j < 2; ++j) {
                int r = wc * 64 + j * 16 + (l & 15);
                int g = kk * 4 + (l >> 4);
                bq0[kk][j] = *(const bf16x8*)&lB[(size_t)r * 64 + ((g ^ (r & 7)) << 3)];
            }
        }
        if (s1)
            stage_half256(BT + (size_t)(n0 + 128) * ldb, ldb, &lds[cur ^ 1][1][128 * 64], kt1, tid);
        __builtin_amdgcn_s_barrier();
        __builtin_amdgcn_s_setprio(1);
#pragma unroll
        for (int kk = 0; kk < 2; ++kk)
#pragma unroll
            for (int i = 0; i < 4; ++i)
#pragma unroll
                for (int j = 0; j < 2; ++j)
                    acc[0][0][i][j] = __builtin_amdgcn_mfma_f32_16x16x32_bf16(af[kk][i], bq0[kk][j], acc[0][0][i][j], 0, 0, 0);
        __builtin_amdgcn_s_setprio(0);
        __builtin_amdgcn_s_barrier();

        // ---- phase 2: reads B(qn1); stage A0(t+2) -> buf cur ----
#pragma unroll
        for (int kk = 0; kk < 2; ++kk)
#pragma unroll
            for (int j = 0; j < 2; ++j) {
                int r = wc * 64 + 32 + j * 16 + (l & 15);
                int g = kk * 4 + (l >> 4);
                bq1[kk][j] = *(const bf16x8*)&lB[(size_t)r * 64 + ((g ^ (r & 7)) << 3)];
            }
        if (s2)
            stage_half256(A + (size_t)m0 * lda, lda, lA, kt2, tid);
        __builtin_amdgcn_s_barrier();
        __builtin_amdgcn_s_setprio(1);
#pragma unroll
        for (int kk = 0; kk < 2; ++kk)
#pragma unroll
            for (int i = 0; i < 4; ++i)
#pragma unroll
                for (int j = 0; j < 2; ++j)
                    acc[0][1][i][j] = __builtin_amdgcn_mfma_f32_16x16x32_bf16(af[kk][i], bq1[kk][j], acc[0][1][i][j], 0, 0, 0);
        __builtin_amdgcn_s_setprio(0);
        __builtin_amdgcn_s_barrier();

        // ---- phase 3: reads A(qm1); stage B0(t+2) -> buf cur ----
#pragma unroll
        for (int kk = 0; kk < 2; ++kk)
#pragma unroll
            for (int i = 0; i < 4; ++i) {
                int r = wr * 128 + 64 + i * 16 + (l & 15);
                int g = kk * 4 + (l >> 4);
                af[kk][i] = *(const bf16x8*)&lA[(size_t)r * 64 + ((g ^ (r & 7)) << 3)];
            }
        if (s2)
            stage_half256(BT + (size_t)n0 * ldb, ldb, lB, kt2, tid);
        __builtin_amdgcn_s_barrier();
        __builtin_amdgcn_s_setprio(1);
#pragma unroll
        for (int kk = 0; kk < 2; ++kk)
#pragma unroll
            for (int i = 0; i < 4; ++i)
#pragma unroll
                for (int j = 0; j < 2; ++j)
                    acc[1][0][i][j] = __builtin_amdgcn_mfma_f32_16x16x32_bf16(af[kk][i], bq0[kk][j], acc[1][0][i][j], 0, 0, 0);
        __builtin_amdgcn_s_setprio(0);
        __builtin_amdgcn_s_barrier();

        // ---- phase 4: MFMA q11; stage A1(t+2) -> buf cur; boundary ----
        __builtin_amdgcn_s_setprio(1);
#pragma unroll
        for (int kk = 0; kk < 2; ++kk)
#pragma unroll
            for (int i = 0; i < 4; ++i)
#pragma unroll
                for (int j = 0; j < 2; ++j)
                    acc[1][1][i][j] = __builtin_amdgcn_mfma_f32_16x16x32_bf16(af[kk][i], bq1[kk][j], acc[1][1][i][j], 0, 0, 0);
        __builtin_amdgcn_s_setprio(0);

        if (s2)
            stage_half256(A + (size_t)(m0 + 128) * lda, lda, lA + 128 * 64, kt2, tid);
        if (s1) {
            if (s2) asm volatile("s_waitcnt vmcnt(6)" ::: "memory");
            else    asm volatile("s_waitcnt vmcnt(0)" ::: "memory");
            __builtin_amdgcn_s_barrier();
        }
    }

    // C/D layout: col = lane&15, row = (lane>>4)*4 + reg
    const int lr = (l >> 4) * 4, lc = l & 15;
#pragma unroll
    for (int qm = 0; qm < 2; ++qm)
#pragma unroll
        for (int i = 0; i < 4; ++i) {
            int row = m0 + wr * 128 + qm * 64 + i * 16 + lr;
#pragma unroll
            for (int qn = 0; qn < 2; ++qn)
#pragma unroll
                for (int j = 0; j < 2; ++j) {
                    int col = n0 + wc * 64 + qn * 32 + j * 16 + lc;
                    u16* p = C + (size_t)row * ldc + col;
#pragma unroll
                    for (int q = 0; q < 4; ++q)
                        p[(size_t)q * ldc] = f2bf(acc[qm][qn][i][j][q]);
                }
        }
}

// ---------------------------------------------------------------------------
__global__ __launch_bounds__(256, 2)
void conv_kernel(const float* __restrict__ x, const u16* __restrict__ Y,
                 const u16* __restrict__ Wbf, const float* __restrict__ bias,
                 float* __restrict__ yout, int b0, int Gb, int nPerBlk, int ldy) {
    __shared__ u16 lh[192 * 72];
    const int colsPerN = Gb * 12;
    const int n0 = blockIdx.x * nPerBlk;
    const int tid = threadIdx.x;
    const int w = tid >> 6, l = tid & 63;
    f32x4 acc[4][3] = {};

    for (int k = 0; k < 5; ++k) {
        __syncthreads();
        if (k == 0) {
            const int tot = nPerBlk * Gb * 64;
            for (int it = tid; it < tot; it += 256) {
                int c = it & 63;
                int bn = it >> 6;
                int bl = bn % Gb;
                int nl = bn / Gb;
                const float* src = x + ((size_t)((b0 + bl) * 64 + c) * 2048 + (n0 + nl)) * 12;
                float4 v0 = *(const float4*)(src + 0);
                float4 v1 = *(const float4*)(src + 4);
                float4 v2 = *(const float4*)(src + 8);
                float vv[12];
                *(float4*)&vv[0] = v0; *(float4*)&vv[4] = v1; *(float4*)&vv[8] = v2;
                u16* d = &lh[(nl * colsPerN + bl * 12) * 72 + c];
#pragma unroll
                for (int t = 0; t < 12; ++t) d[t * 72] = f2bf(vv[t]);
            }
        } else {
            for (int it = tid; it < 1536; it += 256) {
                int e8 = it << 3;
                int c = e8 & 63;
                int jj = e8 >> 6;
                int nl = jj / colsPerN;
                int rem = jj - nl * colsPerN;
                const u16* src = Y + (size_t)((k - 1) * 2048 + n0 + nl) * ldy + rem * 64 + c;
                *(u16x8*)&lh[jj * 72 + c] = *(const u16x8*)src;
            }
        }
        __syncthreads();
#pragma unroll
        for (int kk = 0; kk < 2; ++kk) {
            bf16x8 wf[4], hf[3];
#pragma unroll
            for (int i = 0; i < 4; ++i)
                wf[i] = *(const bf16x8*)&Wbf[(size_t)(k * 64 + i * 16 + (l & 15)) * 64 + kk * 32 + (l >> 4) * 8];
#pragma unroll
            for (int j = 0; j < 3; ++j)
                hf[j] = *(const bf16x8*)&lh[(w * 48 + j * 16 + (l & 15)) * 72 + kk * 32 + (l >> 4) * 8];
#pragma unroll
            for (int i = 0; i < 4; ++i)
#pragma unroll
                for (int j = 0; j < 3; ++j)
                    acc[i][j] = __builtin_amdgcn_mfma_f32_16x16x32_bf16(wf[i], hf[j], acc[i][j], 0, 0, 0);
        }
    }

    const int lr = (l >> 4) * 4, lc = l & 15;
#pragma unroll
    for (int j = 0; j < 3; ++j) {
        int jj = w * 48 + j * 16 + lc;
        int nl = jj / colsPerN;
        int rem = jj - nl * colsPerN;
        int bl = rem / 12;
        int t = rem - bl * 12;
#pragma unroll
        for (int i = 0; i < 4; ++i) {
#pragma unroll
            for (int q = 0; q < 4; ++q) {
                int o = i * 16 + lr + q;
                yout[((size_t)((b0 + bl) * 64 + o) * 2048 + (n0 + nl)) * 12 + t] = acc[i][j][q] + bias[o];
            }
        }
    }
}

// ---------------------------------------------------------------------------
extern "C" void kernel_launch(void* const* d_in, const int* in_sizes, int n_in,
                              void* d_out, int out_size, void* d_ws, size_t ws_size,
                              hipStream_t stream) {
    (void)in_sizes; (void)n_in; (void)out_size;
    const float* x  = (const float*)d_in[0];
    const float* A1 = (const float*)d_in[1];
    const float* A2 = (const float*)d_in[2];
    const float* W  = (const float*)d_in[3];
    const float* bs = (const float*)d_in[4];
    float* y = (float*)d_out;
    char* ws = (char*)d_ws;

    const size_t CHUNK_OFF = 33619968;
    u16* astack = (u16*)ws;
    u16* wbf = (u16*)(ws + 33554432);
    u16* a1t = (u16*)(ws + CHUNK_OFF);
    u16* a2t = a1t + (size_t)2048 * 2048;

    size_t avail = ws_size > CHUNK_OFF ? ws_size - CHUNK_OFF : 0;
    int Gb = 16;
    while (Gb > 1 && (size_t)Gb * 15728640 > avail) Gb >>= 1;
    u16* xtT = (u16*)(ws + CHUNK_OFF);
    u16* Yb = xtT + (size_t)Gb * 768 * 2048;
    int ldy = Gb * 768;
    int nPerBlk = 16 / Gb;

    cvt_w_kernel<<<80, 256, 0, stream>>>(W, wbf);
    cvt_a_kernel<<<2048, 256, 0, stream>>>(A1, A2, astack, a1t, a2t);

    gemm_bt_kernel<<<dim3(16, 16, 2), 256, 0, stream>>>(
        astack, a1t, astack + (size_t)2048 * 2048,
        astack + (size_t)4096 * 2048, a2t, astack + (size_t)6144 * 2048,
        2048, 2048, 2048, 2048);

    for (int b0 = 0; b0 < 16; b0 += Gb) {
        pack_x_kernel<<<Gb * 512, 256, 0, stream>>>(x, xtT, b0, Gb);
        gemm256_kernel<<<dim3(ldy / 256, 32), 512, 0, stream>>>(
            astack, xtT, Yb, 2048, 2048, 2048, ldy);
        conv_kernel<<<128 * Gb, 256, 0, stream>>>(x, Yb, wbf, bs, y, b0, Gb, nPerBlk, ldy);
    }
}